// Round 16
// baseline (2756.458 us; speedup 1.0000x reference)
//
#include <hip/hip_runtime.h>

typedef unsigned short u16;
typedef __attribute__((ext_vector_type(4))) float f32x4;
typedef __attribute__((ext_vector_type(2))) float f32x2;
typedef __attribute__((ext_vector_type(8))) short short8;

#define B_ 32
#define P_ 196
#define T_ 64
#define V_ 32000
#define SLABF 17408   // 68 KB slab stride in floats
#define EXPS  7424    // exp slab stride in floats (32*224 padded)

// Cross-block exchange (proven r4-r15): producers = relaxed agent-scope atomic
// stores (write-through to MALL); consumers = plain cached loads on t-indexed
// slabs (fresh addresses per step -> no stale line; miss fills L2).
#define AT_LOAD(p)     __hip_atomic_load((p), __ATOMIC_RELAXED, __HIP_MEMORY_SCOPE_AGENT)
#define AT_STORE(p,v)  __hip_atomic_store((p), (v), __ATOMIC_RELAXED, __HIP_MEMORY_SCOPE_AGENT)

__device__ __forceinline__ u16 f2bf(float x){
  unsigned int u = __float_as_uint(x);
  u += 0x7FFFu + ((u >> 16) & 1u);
  return (u16)(u >> 16);
}
__device__ __forceinline__ float bf2f(u16 x){
  return __uint_as_float(((unsigned int)x) << 16);
}
__device__ __forceinline__ float sigf(float x){ return 1.0f/(1.0f + __expf(-x)); }
__device__ __forceinline__ float tanhfast(float x){
  float e = __expf(-2.0f*fabsf(x));
  float t = (1.0f - e)/(1.0f + e);
  return x >= 0.0f ? t : -t;
}

// ---------- setup kernels ----------

__global__ __launch_bounds__(256) void k_cvt_bf16(const float* __restrict__ s,
                                                  u16* __restrict__ d, int n8){
  int i = blockIdx.x*256 + threadIdx.x;
  if (i >= n8) return;
  const f32x4* sp = (const f32x4*)(s + (size_t)i*8);
  f32x4 a = sp[0], b = sp[1];
  short8 v;
#pragma unroll
  for (int j=0;j<4;++j){ v[j] = (short)f2bf(a[j]); v[4+j] = (short)f2bf(b[j]); }
  *(short8*)(d + (size_t)i*8) = v;
}

__global__ __launch_bounds__(256) void k_wencT(const float* __restrict__ W, u16* __restrict__ WT){
  int tid = threadIdx.x;
  int kc = tid & 63, a = blockIdx.x*4 + (tid >> 6);
  short8 v;
#pragma unroll
  for (int j=0;j<8;++j) v[j] = (short)f2bf(W[(kc*8+j)*512 + a]);
  *(short8*)(WT + a*512 + kc*8) = v;
}

__global__ __launch_bounds__(256) void k_mean(const float* __restrict__ enc, float* __restrict__ mean){
  int b = blockIdx.x, tid = threadIdx.x;
  f32x2 acc; acc.x = 0.f; acc.y = 0.f;
  for (int p=0;p<P_;++p){
    f32x2 v = *(const f32x2*)(enc + ((size_t)(b*P_+p))*512 + tid*2);
    acc.x += v.x; acc.y += v.y;
  }
  acc.x *= (1.0f/196.0f); acc.y *= (1.0f/196.0f);
  *(f32x2*)(mean + b*512 + tid*2) = acc;
}

__global__ __launch_bounds__(256) void k_init_state(const float* __restrict__ mean,
    const float* __restrict__ Wh, const float* __restrict__ bh,
    const float* __restrict__ Wc, const float* __restrict__ bc,
    float* __restrict__ h0, float* __restrict__ h1,
    float* __restrict__ c0, float* __restrict__ c1){
  int bid = blockIdx.x;
  int which = bid >> 7, r = (bid >> 2) & 31, jg = bid & 3;
  const float* W = which ? Wc : Wh;
  const float* bb = which ? bc : bh;
  __shared__ float m[512];
  for (int i=threadIdx.x; i<512; i+=256) m[i] = mean[r*512 + i];
  __syncthreads();
  int j = jg*256 + threadIdx.x;
  float acc = bb[j];
  for (int e=0;e<512;++e) acc += m[e]*W[e*1024 + j];
  int l = r >> 4;
  int bb2 = ((r & 15) << 1) | (j >> 9);
  int hh = j & 511;
  float* dst = which ? (l ? c1 : c0) : (l ? h1 : h0);
  dst[bb2*512 + hh] = acc;
}

// pack LSTM weights to bf16 in the streaming layout:
// W0bf[(( (g*4+gate)*192 + kc )*64 + ci)*8 + e], row = gate*512+g*64+ci, k = kc*8+e
// W1bf analogous with 128 kc.
__global__ __launch_bounds__(512) void k_pack(const float* __restrict__ Wih0,
    const float* __restrict__ Whh0, const float* __restrict__ Wih1,
    const float* __restrict__ Whh1, u16* __restrict__ W0bf, u16* __restrict__ W1bf){
  int bidx = blockIdx.x, tid = threadIdx.x;
  int ci = tid >> 3, e = tid & 7;
  if (bidx < 6144){
    int kc = bidx % 192, gg = bidx / 192;
    int gate = gg & 3, g = gg >> 2;
    int row = gate*512 + g*64 + ci, k = kc*8 + e;
    float v = (k < 1024) ? Wih0[(size_t)row*1024 + k] : Whh0[(size_t)row*512 + (k-1024)];
    W0bf[(size_t)bidx*512 + tid] = f2bf(v);
  } else {
    int b2 = bidx - 6144;
    int kc = b2 % 128, gg = b2 / 128;
    int gate = gg & 3, g = gg >> 2;
    int row = gate*512 + g*64 + ci, k = kc*8 + e;
    float v = (k < 512) ? Wih1[(size_t)row*512 + k] : Whh1[(size_t)row*512 + (k-512)];
    W1bf[(size_t)b2*512 + tid] = f2bf(v);
  }
}

// ---------- bf16 GEMM (LDS pad 40 u16): C[M][N] = A[M][512]*Bm[N][512]^T + bias ----------
#define LDAP 40
__global__ __launch_bounds__(256) void k_gemm_bf16(
    const u16* __restrict__ A, const u16* __restrict__ Bm,
    const float* __restrict__ bias, float* __restrict__ C, int N){
  __shared__ __align__(16) u16 As[128*LDAP];
  __shared__ __align__(16) u16 Bs[128*LDAP];
  int tid = threadIdx.x, l = tid & 63, w = tid >> 6;
  int m0 = blockIdx.x * 128, n0 = blockIdx.y * 128;
  int wm = w >> 1, wn = w & 1;
  f32x4 acc[4][4];
#pragma unroll
  for (int a=0;a<4;++a)
#pragma unroll
    for (int b=0;b<4;++b) acc[a][b] = (f32x4)0.0f;
  int srow = tid >> 2, schunk = tid & 3;
  const u16* gA = A + (size_t)(m0 + srow)*512 + schunk*8;
  const u16* gB = Bm + (size_t)(n0 + srow)*512 + schunk*8;
  int lr = l & 15, lk = (l >> 4) * 8;
  for (int k0 = 0; k0 < 512; k0 += 32){
    short8 va0 = *(const short8*)(gA + k0);
    short8 va1 = *(const short8*)(gA + (size_t)64*512 + k0);
    short8 vb0 = *(const short8*)(gB + k0);
    short8 vb1 = *(const short8*)(gB + (size_t)64*512 + k0);
    __syncthreads();
    *(short8*)(As + srow*LDAP + schunk*8) = va0;
    *(short8*)(As + (64+srow)*LDAP + schunk*8) = va1;
    *(short8*)(Bs + srow*LDAP + schunk*8) = vb0;
    *(short8*)(Bs + (64+srow)*LDAP + schunk*8) = vb1;
    __syncthreads();
    short8 af[4], bfv[4];
#pragma unroll
    for (int mt=0; mt<4; ++mt) af[mt]  = *(const short8*)(As + (wm*64 + mt*16 + lr)*LDAP + lk);
#pragma unroll
    for (int nt=0; nt<4; ++nt) bfv[nt] = *(const short8*)(Bs + (wn*64 + nt*16 + lr)*LDAP + lk);
#pragma unroll
    for (int mt=0; mt<4; ++mt)
#pragma unroll
      for (int nt=0; nt<4; ++nt)
        acc[mt][nt] = __builtin_amdgcn_mfma_f32_16x16x32_bf16(af[mt], bfv[nt], acc[mt][nt], 0, 0, 0);
  }
#pragma unroll
  for (int mt=0; mt<4; ++mt){
    int row = m0 + wm*64 + mt*16 + ((l >> 4) << 2);
#pragma unroll
    for (int nt=0; nt<4; ++nt){
      int col = n0 + wn*64 + nt*16 + (l & 15);
      float bv = bias[col];
#pragma unroll
      for (int j=0;j<4;++j)
        C[(size_t)(row + j)*N + col] = acc[mt][nt][j] + bv;
    }
  }
}

// ---------- persistent recurrence kernel: block = (batch, cell-slice) ----------

struct RA {
  const int* caps; const float* embW; const float* Wdec; const float* bdec;
  const float* Wfull; const float* bfull;
  const u16* encattBF; const u16* encBF;     // encBF = A_enc (bf16 encoder_out)
  const u16* W0bf; const u16* W1bf;
  const float* bih0; const float* bhh0; const float* bih1; const float* bhh1;
  float* h0g; float* h1g; float* att2g; float* ctxg; float* expg;
  const float* c0init; const float* c1init;
  u16* h1_all; int* sync;
};

// No grid-wide barriers: 8-block per-batch group barrier through MALL flags.
__global__ __launch_bounds__(512) void k_recur(RA a){
  int bid = blockIdx.x, tid = threadIdx.x;
  int lane = tid & 63, wv = tid >> 6;     // lane = ci/col, wv = k-slice/wave
  int b = bid >> 3, g = bid & 7;          // batch, slice (bid&7 -> XCD-aligned)

  __shared__ __align__(16) float xs[1536];    // x staging: [emb|ctx|h0] / [h0|h1]
  __shared__ float red[2048];                 // phase scratch / gate partials
  __shared__ float alph[224];
  __shared__ float c0s[64], c1s[64];
  __shared__ float SinvS;
  __shared__ int capS;

  if (tid < 64){
    c0s[tid] = a.c0init[b*512 + g*64 + tid];
    c1s[tid] = a.c1init[b*512 + g*64 + tid];
  }
  __syncthreads();

  int* gf = a.sync;   // group flags: [(b*8+g)*32]
#define GRPBAR(gen_) { \
    __syncthreads(); \
    if (tid == 0) AT_STORE(&gf[(b*8 + g)*32], (gen_)); \
    if (tid < 8){ while (AT_LOAD(&gf[(b*8 + tid)*32]) < (gen_)) __builtin_amdgcn_s_sleep(1); } \
    __syncthreads(); \
    asm volatile("" ::: "memory"); }

  for (int t = 0; t < T_; ++t){
    const float* h1_rd = a.h1g + (size_t)t*SLABF;
    const float* h0_rd = a.h0g + (size_t)t*SLABF;
    float*       h0_wr = a.h0g + (size_t)(t+1)*SLABF;
    float*       h1_wr = a.h1g + (size_t)(t+1)*SLABF;
    float*       at_wr = a.att2g + (size_t)t*SLABF;
    const float* at_rd = at_wr;
    float*       cx_wr = a.ctxg + (size_t)t*SLABF;
    const float* cx_rd = cx_wr;
    float*       ex_wr = a.expg + (size_t)t*EXPS;
    const float* ex_rd = ex_wr;
    int gen0 = t*5;

    // stage emb row for this batch (consumed in P4)
    if (tid == 0) capS = a.caps[b*T_ + t];
    __syncthreads();
    xs[tid] = a.embW[(size_t)capS*512 + tid];

    // ---- P1: att2 slice [g*64, g*64+64) for batch b (f32 Wdec) ----
    {
      float* h1s = red; float* gp = red + 512;
      h1s[tid] = h1_rd[b*512 + tid];
      __syncthreads();
      float acc = 0.f;
      const float* wpd = a.Wdec + (size_t)(wv*64)*512 + g*64 + lane;
#pragma unroll 8
      for (int i=0;i<64;++i) acc = fmaf(h1s[wv*64+i], wpd[(size_t)i*512], acc);
      gp[wv*64+lane] = acc;
      __syncthreads();
      if (tid < 64){
        float s = a.bdec[g*64+tid];
#pragma unroll
        for (int k=0;k<8;++k) s += gp[k*64+tid];
        AT_STORE(&at_wr[b*512 + g*64 + tid], s);
      }
    }
    GRPBAR(gen0+1);

    // ---- P2: logits slice -> exp ----
    {
      float* att2s = red;
      att2s[tid] = at_rd[b*512 + tid];
      __syncthreads();
      float a2[8], wf[8];
#pragma unroll
      for (int j=0;j<8;++j){ a2[j] = att2s[lane*8+j]; wf[j] = a.Wfull[lane*8+j]; }
      float bf0 = a.bfull[0];
      int np = (g < 4) ? 25 : 24;
      int base = (g < 4) ? g*25 : 100 + (g-4)*24;
      for (int i=0;i<4;++i){
        int is = wv + i*8;
        if (is < np){
          int p = base + is;
          const u16* ep = a.encattBF + ((size_t)(b*P_ + p))*512 + lane*8;
          short8 ev = *(const short8*)ep;
          float s = 0.f;
#pragma unroll
          for (int j=0;j<8;++j)
            s += fmaxf(bf2f((u16)ev[j]) + a2[j], 0.f) * wf[j];
#pragma unroll
          for (int o=32;o>=1;o>>=1) s += __shfl_xor(s, o);
          if (lane == 0) AT_STORE(&ex_wr[b*224 + p], __expf(s + bf0));
        }
      }
    }
    GRPBAR(gen0+2);

    // ---- P3: softmax (local) + ctx slice ----
    {
      if (tid < 224) alph[tid] = (tid < P_) ? ex_rd[b*224 + tid] : 0.f;
      __syncthreads();
      if (wv == 0){
        float v = 0.f;
#pragma unroll
        for (int i=0;i<4;++i){ int idx = lane + 64*i; if (idx < 224) v += alph[idx]; }
#pragma unroll
        for (int o=32;o>=1;o>>=1) v += __shfl_xor(v, o);
        if (lane == 0) SinvS = 1.0f / v;
      }
      __syncthreads();
      float* gp = red + 512;
      float acc = 0.f;
      for (int i=0;i<25;++i){
        int p = wv + 8*i;
        if (p < P_)
          acc = fmaf(alph[p], bf2f(a.encBF[((size_t)(b*P_ + p))*512 + g*64 + lane]), acc);
      }
      gp[wv*64+lane] = acc;
      __syncthreads();
      if (tid < 64){
        float s = 0.f;
#pragma unroll
        for (int k=0;k<8;++k) s += gp[k*64+tid];
        AT_STORE(&cx_wr[b*512 + g*64 + tid], s * SinvS);
      }
    }
    GRPBAR(gen0+3);

    // ---- P4: L0 gates for cells g*64..+63 (weights streamed bf16 from L2) ----
    {
      xs[512 + tid]  = cx_rd[b*512 + tid];
      xs[1024 + tid] = h0_rd[b*512 + tid];
      __syncthreads();
      float ac[4];
#pragma unroll
      for (int r=0;r<4;++r) ac[r] = 0.f;
      const u16* w0base = a.W0bf + ((size_t)(g*4)*192)*512 + lane*8;
#pragma unroll 4
      for (int j=0;j<24;++j){
        int kc = wv*24 + j;
        f32x4 xlo = *(const f32x4*)&xs[kc*8];
        f32x4 xhi = *(const f32x4*)&xs[kc*8+4];
#pragma unroll
        for (int gate=0; gate<4; ++gate){
          short8 w8 = *(const short8*)(w0base + ((size_t)(gate*192 + kc))*512);
          float s = ac[gate];
          s = fmaf(bf2f((u16)w8[0]), xlo.x, s);
          s = fmaf(bf2f((u16)w8[1]), xlo.y, s);
          s = fmaf(bf2f((u16)w8[2]), xlo.z, s);
          s = fmaf(bf2f((u16)w8[3]), xlo.w, s);
          s = fmaf(bf2f((u16)w8[4]), xhi.x, s);
          s = fmaf(bf2f((u16)w8[5]), xhi.y, s);
          s = fmaf(bf2f((u16)w8[6]), xhi.z, s);
          s = fmaf(bf2f((u16)w8[7]), xhi.w, s);
          ac[gate] = s;
        }
      }
      __syncthreads();
#pragma unroll
      for (int gate=0; gate<4; ++gate) red[(gate*8 + wv)*64 + lane] = ac[gate];
      __syncthreads();
      if (tid < 64){
        int cell = g*64 + tid;
        float G[4];
#pragma unroll
        for (int gate=0; gate<4; ++gate){
          float s = a.bih0[gate*512+cell] + a.bhh0[gate*512+cell];
#pragma unroll
          for (int ks=0; ks<8; ++ks) s += red[(gate*8+ks)*64 + tid];
          G[gate] = s;
        }
        float cp = c0s[tid];
        float cn = sigf(G[1])*cp + sigf(G[0])*tanhfast(G[2]);
        float hn = sigf(G[3])*tanhfast(cn);
        c0s[tid] = cn;
        AT_STORE(&h0_wr[b*512 + cell], hn);
      }
    }
    GRPBAR(gen0+4);

    // ---- P5: L1 gates ----
    {
      xs[tid]       = h0_wr[b*512 + tid];   // fresh slab (written this step)
      xs[512 + tid] = h1_rd[b*512 + tid];
      __syncthreads();
      float ac[4];
#pragma unroll
      for (int r=0;r<4;++r) ac[r] = 0.f;
      const u16* w1base = a.W1bf + ((size_t)(g*4)*128)*512 + lane*8;
#pragma unroll 4
      for (int j=0;j<16;++j){
        int kc = wv*16 + j;
        f32x4 xlo = *(const f32x4*)&xs[kc*8];
        f32x4 xhi = *(const f32x4*)&xs[kc*8+4];
#pragma unroll
        for (int gate=0; gate<4; ++gate){
          short8 w8 = *(const short8*)(w1base + ((size_t)(gate*128 + kc))*512);
          float s = ac[gate];
          s = fmaf(bf2f((u16)w8[0]), xlo.x, s);
          s = fmaf(bf2f((u16)w8[1]), xlo.y, s);
          s = fmaf(bf2f((u16)w8[2]), xlo.z, s);
          s = fmaf(bf2f((u16)w8[3]), xlo.w, s);
          s = fmaf(bf2f((u16)w8[4]), xhi.x, s);
          s = fmaf(bf2f((u16)w8[5]), xhi.y, s);
          s = fmaf(bf2f((u16)w8[6]), xhi.z, s);
          s = fmaf(bf2f((u16)w8[7]), xhi.w, s);
          ac[gate] = s;
        }
      }
      __syncthreads();
#pragma unroll
      for (int gate=0; gate<4; ++gate) red[(gate*8 + wv)*64 + lane] = ac[gate];
      __syncthreads();
      if (tid < 64){
        int cell = g*64 + tid;
        float G[4];
#pragma unroll
        for (int gate=0; gate<4; ++gate){
          float s = a.bih1[gate*512+cell] + a.bhh1[gate*512+cell];
#pragma unroll
          for (int ks=0; ks<8; ++ks) s += red[(gate*8+ks)*64 + tid];
          G[gate] = s;
        }
        float cp = c1s[tid];
        float cn = sigf(G[1])*cp + sigf(G[0])*tanhfast(G[2]);
        float hn = sigf(G[3])*tanhfast(cn);
        c1s[tid] = cn;
        AT_STORE(&h1_wr[b*512 + cell], hn);
        a.h1_all[((size_t)(b*T_ + t))*512 + cell] = f2bf(hn);
      }
    }
    GRPBAR(gen0+5);
  }
#undef GRPBAR
}

// ---------- host ----------

extern "C" void kernel_launch(void* const* d_in, const int* in_sizes, int n_in,
                              void* d_out, int out_size, void* d_ws, size_t ws_size,
                              hipStream_t stream){
  const float* enc   = (const float*)d_in[0];
  const int*   caps  = (const int*)d_in[1];
  const float* embW  = (const float*)d_in[2];
  const float* fc_b  = (const float*)d_in[3];
  const float* Wenc  = (const float*)d_in[4];
  const float* benc  = (const float*)d_in[5];
  const float* Wdec  = (const float*)d_in[6];
  const float* bdec  = (const float*)d_in[7];
  const float* Wfull = (const float*)d_in[8];
  const float* bfull = (const float*)d_in[9];
  const float* Wih0  = (const float*)d_in[10];
  const float* Whh0  = (const float*)d_in[11];
  const float* bih0  = (const float*)d_in[12];
  const float* bhh0  = (const float*)d_in[13];
  const float* Wih1  = (const float*)d_in[14];
  const float* Whh1  = (const float*)d_in[15];
  const float* bih1  = (const float*)d_in[16];
  const float* bhh1  = (const float*)d_in[17];
  const float* Winh  = (const float*)d_in[18];
  const float* binh  = (const float*)d_in[19];
  const float* Winc  = (const float*)d_in[20];
  const float* binc  = (const float*)d_in[21];
  float* out = (float*)d_out;

  char* wsp = (char*)d_ws;
  size_t off = 0;
  auto alloc = [&](size_t bytes)->char*{
    char* p = wsp + off;
    off += (bytes + 255) & ~(size_t)255;
    return p;
  };
  u16*   A_enc    = (u16*)  alloc((size_t)6272*512*2);
  u16*   emb_bf   = (u16*)  alloc((size_t)V_*512*2);
  u16*   WencT    = (u16*)  alloc((size_t)512*512*2);
  float* encatt   = (float*)alloc((size_t)6272*512*4);
  u16*   encattBF = (u16*)  alloc((size_t)6272*512*2);
  float* meanb    = (float*)alloc((size_t)32*512*4);
  u16*   W0bf     = (u16*)  alloc((size_t)2048*1536*2);
  u16*   W1bf     = (u16*)  alloc((size_t)2048*1024*2);
  float* h0g      = (float*)alloc((size_t)65*SLABF*4);
  float* h1g      = (float*)alloc((size_t)65*SLABF*4);
  float* att2g    = (float*)alloc((size_t)65*SLABF*4);
  float* ctxg     = (float*)alloc((size_t)65*SLABF*4);
  float* expg     = (float*)alloc((size_t)65*EXPS*4);
  float* c0init   = (float*)alloc(32*512*4);
  float* c1init   = (float*)alloc(32*512*4);
  u16*   h1_all   = (u16*)  alloc((size_t)2048*512*2);
  int*   syncA    = (int*)  alloc(8192*4);
  if (off > ws_size) return;

  // setup
  hipMemsetAsync(syncA, 0, 8192*4, stream);
  k_cvt_bf16<<<1568, 256, 0, stream>>>(enc, A_enc, 401408);
  k_cvt_bf16<<<8000, 256, 0, stream>>>(embW, emb_bf, 2048000);
  k_wencT   <<<128, 256, 0, stream>>>(Wenc, WencT);
  k_mean    <<<32, 256, 0, stream>>>(enc, meanb);
  k_init_state<<<256, 256, 0, stream>>>(meanb, Winh, binh, Winc, binc,
                                        h0g, h1g, c0init, c1init);   // slot 0 = init
  k_pack<<<10240, 512, 0, stream>>>(Wih0, Whh0, Wih1, Whh1, W0bf, W1bf);
  k_gemm_bf16<<<dim3(49, 4), 256, 0, stream>>>(A_enc, WencT, benc, encatt, 512);
  k_cvt_bf16<<<1568, 256, 0, stream>>>(encatt, encattBF, 401408);

  // persistent recurrence (cooperative: guarantees co-residency of all groups)
  RA ra;
  ra.caps = caps; ra.embW = embW; ra.Wdec = Wdec; ra.bdec = bdec;
  ra.Wfull = Wfull; ra.bfull = bfull;
  ra.encattBF = encattBF; ra.encBF = A_enc;
  ra.W0bf = W0bf; ra.W1bf = W1bf;
  ra.bih0 = bih0; ra.bhh0 = bhh0; ra.bih1 = bih1; ra.bhh1 = bhh1;
  ra.h0g = h0g; ra.h1g = h1g; ra.att2g = att2g; ra.ctxg = ctxg; ra.expg = expg;
  ra.c0init = c0init; ra.c1init = c1init;
  ra.h1_all = h1_all; ra.sync = syncA;
  void* kp[] = { &ra };
  hipLaunchCooperativeKernel((const void*)k_recur, dim3(256), dim3(512), kp, 0, stream);

  // deferred tied-weight projection: out[2048][32000] = h1_all @ emb_W^T + fc_b
  k_gemm_bf16<<<dim3(16, 250), 256, 0, stream>>>(h1_all, emb_bf, fc_b, out, V_);
}